// Round 1
// baseline (746.616 us; speedup 1.0000x reference)
//
#include <hip/hip_runtime.h>
#include <hip/hip_bf16.h>
#include <math.h>

#define DEV __device__ __forceinline__

static DEV float softplus_f(float x){ return fmaxf(x,0.f) + log1pf(expf(-fabsf(x))); }
static DEV float logsig_f(float x){ return fminf(x,0.f) - log1pf(expf(-fabsf(x))); }
static DEV float silu_f(float x){ return x / (1.f + expf(-x)); }

// ---------------- LayerNorm over rows of width D ----------------
__global__ void ln_rows(const float* __restrict__ in, float* __restrict__ out,
                        const float* __restrict__ s, const float* __restrict__ b, int D)
{
  int r = blockIdx.x;
  const float* x = in + (size_t)r * D;
  float lsum = 0.f, lsq = 0.f;
  for (int i = threadIdx.x; i < D; i += blockDim.x){ float v = x[i]; lsum += v; lsq += v*v; }
  #pragma unroll
  for (int o = 32; o > 0; o >>= 1){ lsum += __shfl_down(lsum, o); lsq += __shfl_down(lsq, o); }
  __shared__ float s1[4], s2[4];
  int wid = threadIdx.x >> 6, lane = threadIdx.x & 63;
  if (lane == 0){ s1[wid] = lsum; s2[wid] = lsq; }
  __syncthreads();
  if (threadIdx.x == 0){ float a=0.f,c=0.f; for (int w=0; w<4; ++w){ a+=s1[w]; c+=s2[w]; } s1[0]=a; s2[0]=c; }
  __syncthreads();
  float mean = s1[0] / D, var = s2[0] / D - mean*mean;
  float rstd = rsqrtf(var + 1e-5f);
  float* o = out + (size_t)r * D;
  for (int i = threadIdx.x; i < D; i += blockDim.x) o[i] = (x[i]-mean)*rstd*s[i] + b[i];
}

// ---------------- generic fp32 GEMM: C[N,M] = scale*(A[N,K] @ B[K,M]) (+skip) ----------------
#define BM 64
#define BN 64
#define BKG 16
__global__ __launch_bounds__(256) void gemm_f32(
    const float* __restrict__ A, int lda,
    const float* __restrict__ Bw,          // K x M row-major (ldb = M)
    float* __restrict__ C, int ldc,
    int N, int K, int M,
    float scale, const float* __restrict__ skip, int ldskip)
{
  __shared__ float As[BKG][BM];
  __shared__ float Bs[BKG][BN];
  int bx = blockIdx.x, by = blockIdx.y;
  int tid = threadIdx.x;
  int tx = tid & 15, ty = tid >> 4;
  int row0 = by * BM, col0 = bx * BN;
  float acc[4][4] = {};
  for (int k0 = 0; k0 < K; k0 += BKG){
    {
      int r  = tid >> 2;
      int kq = (tid & 3) * 4;
      const float* ap = A + (size_t)(row0 + r) * lda + k0 + kq;
      float4 av = *(const float4*)ap;
      As[kq+0][r] = av.x; As[kq+1][r] = av.y; As[kq+2][r] = av.z; As[kq+3][r] = av.w;
      int kr = tid >> 4;
      int c  = (tid & 15) * 4;
      const float* bp = Bw + (size_t)(k0 + kr) * M + col0 + c;
      *(float4*)&Bs[kr][c] = *(const float4*)bp;
    }
    __syncthreads();
    #pragma unroll
    for (int kk = 0; kk < BKG; ++kk){
      float4 a4 = *(const float4*)&As[kk][ty*4];
      float4 b4 = *(const float4*)&Bs[kk][tx*4];
      float a[4] = {a4.x, a4.y, a4.z, a4.w};
      float b[4] = {b4.x, b4.y, b4.z, b4.w};
      #pragma unroll
      for (int i = 0; i < 4; ++i)
        #pragma unroll
        for (int j = 0; j < 4; ++j)
          acc[i][j] = fmaf(a[i], b[j], acc[i][j]);
    }
    __syncthreads();
  }
  #pragma unroll
  for (int i = 0; i < 4; ++i){
    int r = row0 + ty*4 + i;
    float* cp = C + (size_t)r * ldc + col0 + tx*4;
    float4 o;
    o.x = acc[i][0]*scale; o.y = acc[i][1]*scale; o.z = acc[i][2]*scale; o.w = acc[i][3]*scale;
    if (skip){
      const float* sp = skip + (size_t)r * ldskip + col0 + tx*4;
      o.x += sp[0]; o.y += sp[1]; o.z += sp[2]; o.w += sp[3];
    }
    *(float4*)cp = o;
  }
}

// ---------------- input/forget gate preactivations: ipfp[r][0..7]=ip, [8..15]=fp ----------------
__global__ void ifgate(const float* __restrict__ xp,
                       const float* __restrict__ Wi, const float* __restrict__ bi,
                       const float* __restrict__ Wf, const float* __restrict__ bf,
                       float* __restrict__ ipfp)
{
  int r = blockIdx.x, tid = threadIdx.x;
  __shared__ float xs[1024];
  const float* xrow = xp + (size_t)r * 2048;   // xm = first 1024 cols
  for (int i = tid; i < 1024; i += 256) xs[i] = xrow[i];
  __syncthreads();
  int o = tid & 15, chunk = tid >> 4;
  const float* W = (o < 8) ? Wi : Wf;
  int oc = (o < 8) ? o : o - 8;
  float p = 0.f;
  #pragma unroll 8
  for (int u = 0; u < 64; ++u){ int kk = chunk*64 + u; p = fmaf(xs[kk], W[kk*8 + oc], p); }
  __shared__ float red[16][17];
  red[chunk][o] = p;
  __syncthreads();
  if (tid < 16){
    float sum = 0.f;
    for (int c2 = 0; c2 < 16; ++c2) sum += red[c2][tid];
    int oc2 = (tid < 8) ? tid : tid - 8;
    sum += (tid < 8) ? bi[oc2] : bf[oc2];
    ipfp[r*16 + tid] = sum;
  }
}

// ---------------- gate scan: alpha_s = ip_s - F_s, Mt_t = relu(running max alpha) ----------------
__global__ void scan_gates(const float* __restrict__ ipfp,
                           float* __restrict__ alpha, float* __restrict__ Mt)
{
  int bh = blockIdx.x; int b = bh >> 3, h = bh & 7;
  int lane = threadIdx.x;                 // 64 threads, 4 timesteps each
  float lf[4], ip[4];
  #pragma unroll
  for (int u = 0; u < 4; ++u){
    int t = lane*4 + u, r = b*256 + t;
    ip[u] = ipfp[r*16 + h];
    lf[u] = logsig_f(ipfp[r*16 + 8 + h]);
  }
  float c0 = lf[0], c1 = c0+lf[1], c2 = c1+lf[2], c3 = c2+lf[3];
  float tot = c3, pre = tot;
  #pragma unroll
  for (int o = 1; o < 64; o <<= 1){ float v = __shfl_up(pre, o); if (lane >= o) pre += v; }
  float excl = pre - tot;
  float F[4] = {excl+c0, excl+c1, excl+c2, excl+c3};
  float al[4];
  #pragma unroll
  for (int u = 0; u < 4; ++u) al[u] = ip[u] - F[u];
  float lm[4];
  lm[0] = al[0]; lm[1] = fmaxf(lm[0], al[1]); lm[2] = fmaxf(lm[1], al[2]); lm[3] = fmaxf(lm[2], al[3]);
  float pm = lm[3];
  #pragma unroll
  for (int o = 1; o < 64; o <<= 1){ float v = __shfl_up(pm, o); if (lane >= o) pm = fmaxf(pm, v); }
  float pmexcl = __shfl_up(pm, 1);
  if (lane == 0) pmexcl = -3.4e38f;
  int base = bh*256 + lane*4;
  #pragma unroll
  for (int u = 0; u < 4; ++u){
    alpha[base+u] = al[u];
    Mt[base+u] = fmaxf(0.f, fmaxf(pmexcl, lm[u]));
  }
}

// ---------------- fused causal weighted attention (layer 0, all t) + epilogue ----------------
__global__ __launch_bounds__(256) void attn_l0(
    const float* __restrict__ q, const float* __restrict__ k, const float* __restrict__ v,
    const float* __restrict__ alpha, const float* __restrict__ Mt,
    const float* __restrict__ xp, const float* __restrict__ gn_s, const float* __restrict__ gn_b,
    float* __restrict__ gated)
{
  int blk = blockIdx.x;                    // ((b*8+h)*8 + tt)
  int tt = blk & 7, h = (blk >> 3) & 7, b = blk >> 6;
  int t0 = tt * 32;
  int tid = threadIdx.x;
  int bhT = ((b*8 + h) << 8);

  __shared__ float Qs[32][132];
  __shared__ float Ks[32][132];
  __shared__ float Vs[32][132];
  __shared__ float Ss[32][33];
  __shared__ float redS[8][32];
  __shared__ float redQ[8][32];

  { // load Q tile
    int rl = tid >> 3, c0 = (tid & 7) * 16;
    const float* qp = q + ((size_t)(b*256 + t0 + rl))*1024 + h*128 + c0;
    float4* dst = (float4*)&Qs[rl][c0];
    #pragma unroll
    for (int u = 0; u < 4; ++u) dst[u] = ((const float4*)qp)[u];
  }

  int tx = tid & 15, ty = tid >> 4;
  int tl = tid & 31, g = tid >> 5;
  float acc[16] = {};
  float den = 0.f;
  int ntile = tt + 1;

  for (int it = 0; it < ntile; ++it){
    int s0 = it * 32;
    { // load K,V tiles
      int rl = tid >> 3, c0 = (tid & 7) * 16;
      const float* kp = k + ((size_t)(b*256 + s0 + rl))*1024 + h*128 + c0;
      const float* vp = v + ((size_t)(b*256 + s0 + rl))*1024 + h*128 + c0;
      float4* kd = (float4*)&Ks[rl][c0];
      float4* vd = (float4*)&Vs[rl][c0];
      #pragma unroll
      for (int u = 0; u < 4; ++u){ kd[u] = ((const float4*)kp)[u]; vd[u] = ((const float4*)vp)[u]; }
    }
    __syncthreads();
    // phase A: 2t x 2s scores
    float s00=0.f, s01=0.f, s10=0.f, s11=0.f;
    #pragma unroll 8
    for (int d = 0; d < 128; d += 4){
      float4 qa0 = *(const float4*)&Qs[ty*2+0][d];
      float4 qa1 = *(const float4*)&Qs[ty*2+1][d];
      float4 kb0 = *(const float4*)&Ks[tx*2+0][d];
      float4 kb1 = *(const float4*)&Ks[tx*2+1][d];
      s00 += qa0.x*kb0.x + qa0.y*kb0.y + qa0.z*kb0.z + qa0.w*kb0.w;
      s01 += qa0.x*kb1.x + qa0.y*kb1.y + qa0.z*kb1.z + qa0.w*kb1.w;
      s10 += qa1.x*kb0.x + qa1.y*kb0.y + qa1.z*kb0.z + qa1.w*kb0.w;
      s11 += qa1.x*kb1.x + qa1.y*kb1.y + qa1.z*kb1.z + qa1.w*kb1.w;
    }
    #pragma unroll
    for (int i = 0; i < 2; ++i){
      int st = t0 + ty*2 + i;
      float mt = Mt[bhT + st];
      float sv[2] = { (i==0)? s00 : s10, (i==0)? s01 : s11 };
      #pragma unroll
      for (int j = 0; j < 2; ++j){
        int ss = s0 + tx*2 + j;
        float a = 0.f;
        if (ss <= st) a = expf(alpha[bhT + ss] - mt) * sv[j];
        Ss[ty*2+i][tx*2+j] = a;
      }
    }
    __syncthreads();
    // phase B: PV + row sum
    #pragma unroll 4
    for (int sl = 0; sl < 32; ++sl){
      float a = Ss[tl][sl];
      den += a;
      const float4* vr = (const float4*)&Vs[sl][g*16];
      float4 v0 = vr[0], v1 = vr[1], v2 = vr[2], v3 = vr[3];
      acc[0]  = fmaf(a, v0.x, acc[0]);  acc[1]  = fmaf(a, v0.y, acc[1]);
      acc[2]  = fmaf(a, v0.z, acc[2]);  acc[3]  = fmaf(a, v0.w, acc[3]);
      acc[4]  = fmaf(a, v1.x, acc[4]);  acc[5]  = fmaf(a, v1.y, acc[5]);
      acc[6]  = fmaf(a, v1.z, acc[6]);  acc[7]  = fmaf(a, v1.w, acc[7]);
      acc[8]  = fmaf(a, v2.x, acc[8]);  acc[9]  = fmaf(a, v2.y, acc[9]);
      acc[10] = fmaf(a, v2.z, acc[10]); acc[11] = fmaf(a, v2.w, acc[11]);
      acc[12] = fmaf(a, v3.x, acc[12]); acc[13] = fmaf(a, v3.y, acc[13]);
      acc[14] = fmaf(a, v3.z, acc[14]); acc[15] = fmaf(a, v3.w, acc[15]);
    }
    __syncthreads();
  }
  den = fmaxf(fabsf(den), 1.0f);
  float inv = 1.0f / den;
  float hh[16], ps = 0.f, pq = 0.f;
  #pragma unroll
  for (int j = 0; j < 16; ++j){ hh[j] = acc[j]*inv; ps += hh[j]; pq += hh[j]*hh[j]; }
  redS[g][tl] = ps; redQ[g][tl] = pq;
  __syncthreads();
  float sum = 0.f, sq = 0.f;
  #pragma unroll
  for (int g2 = 0; g2 < 8; ++g2){ sum += redS[g2][tl]; sq += redQ[g2][tl]; }
  float mean = sum * (1.f/128.f);
  float var  = sq  * (1.f/128.f) - mean*mean;
  float rstd = rsqrtf(var + 1e-5f);
  int r = b*256 + t0 + tl;
  const float* zrow = xp + (size_t)r*2048 + 1024 + h*128 + g*16;
  float* grow = gated + (size_t)r*1024 + h*128 + g*16;
  const float* gs = gn_s + h*128 + g*16;
  const float* gb = gn_b + h*128 + g*16;
  #pragma unroll
  for (int j = 0; j < 16; ++j){
    float valn = (hh[j]-mean)*rstd*gs[j] + gb[j];
    grow[j] = valn * silu_f(zrow[j]);
  }
}

// ---------------- layer 1: q at last step only (GEMV) ----------------
__global__ void qlast_kernel(const float* __restrict__ xp, const float* __restrict__ Wq,
                             float* __restrict__ q1last)
{
  __shared__ float xs[1024];
  int b = blockIdx.y, j = blockIdx.x*256 + threadIdx.x;
  const float* xrow = xp + (size_t)(b*256 + 255) * 2048;
  for (int i = threadIdx.x; i < 1024; i += 256) xs[i] = xrow[i];
  __syncthreads();
  float acc = 0.f;
  #pragma unroll 4
  for (int i = 0; i < 1024; ++i) acc = fmaf(xs[i], Wq[(size_t)i*1024 + j], acc);
  q1last[b*1024 + j] = acc;
}

// ---------------- layer 1: last-step attention + epilogue ----------------
__global__ __launch_bounds__(256) void attn_l1(
    const float* __restrict__ q1, const float* __restrict__ k1, const float* __restrict__ v1,
    const float* __restrict__ alpha, const float* __restrict__ Mt,
    const float* __restrict__ xp1, const float* __restrict__ gn_s, const float* __restrict__ gn_b,
    float* __restrict__ gated1)
{
  int bh = blockIdx.x; int b = bh >> 3, h = bh & 7;
  int tid = threadIdx.x;
  __shared__ float qsh[128];
  __shared__ float as[256];
  __shared__ float red2[2][128];
  __shared__ float hh_sh[128];
  __shared__ float wred[4];
  __shared__ float dsh, msh, rsh;
  if (tid < 128) qsh[tid] = q1[b*1024 + h*128 + tid];
  __syncthreads();
  float val;
  {
    int s = tid;
    const float* kp = k1 + ((size_t)(b*256 + s))*1024 + h*128;
    float sc = 0.f;
    #pragma unroll
    for (int d = 0; d < 128; d += 4){
      float4 kv = *(const float4*)(kp + d);
      sc += qsh[d]*kv.x + qsh[d+1]*kv.y + qsh[d+2]*kv.z + qsh[d+3]*kv.w;
    }
    float w = expf(alpha[bh*256 + s] - Mt[bh*256 + 255]);
    val = w * sc;
    as[s] = val;
  }
  // block-reduce sum(val) -> den
  float d = val;
  #pragma unroll
  for (int o = 32; o > 0; o >>= 1) d += __shfl_down(d, o);
  int wid = tid >> 6, lane = tid & 63;
  if (lane == 0) wred[wid] = d;
  __syncthreads();
  if (tid == 0){ float sum = wred[0]+wred[1]+wred[2]+wred[3]; dsh = fmaxf(fabsf(sum), 1.0f); }
  __syncthreads();
  // num
  int dh = tid & 127, half = tid >> 7;
  float np = 0.f;
  const float* vbase = v1 + ((size_t)(b*256))*1024 + h*128 + dh;
  for (int s2 = half*128; s2 < half*128 + 128; ++s2)
    np = fmaf(as[s2], vbase[(size_t)s2*1024], np);
  red2[half][dh] = np;
  __syncthreads();
  if (tid < 128) hh_sh[tid] = (red2[0][tid] + red2[1][tid]) / dsh;
  __syncthreads();
  if (tid < 64){
    float a = hh_sh[tid], c = hh_sh[tid+64];
    float s1 = a + c, s2v = a*a + c*c;
    #pragma unroll
    for (int o = 32; o > 0; o >>= 1){ s1 += __shfl_down(s1, o); s2v += __shfl_down(s2v, o); }
    if (tid == 0){
      float mean = s1*(1.f/128.f);
      float var = s2v*(1.f/128.f) - mean*mean;
      msh = mean; rsh = rsqrtf(var + 1e-5f);
    }
  }
  __syncthreads();
  if (tid < 128){
    int i = h*128 + tid;
    float valn = (hh_sh[tid]-msh)*rsh*gn_s[i] + gn_b[i];
    float z = xp1[(size_t)(b*256 + 255)*2048 + 1024 + i];
    gated1[b*1024 + i] = valn * silu_f(z);
  }
}

// ---------------- last-step down proj + skip ----------------
__global__ void downlast_kernel(const float* __restrict__ gated1, const float* __restrict__ Wd,
                                const float* __restrict__ h0, float* __restrict__ hfinal)
{
  __shared__ float gs[1024];
  int b = blockIdx.y, j = blockIdx.x*256 + threadIdx.x;
  for (int i = threadIdx.x; i < 1024; i += 256) gs[i] = gated1[b*1024 + i];
  __syncthreads();
  float acc = 0.f;
  #pragma unroll 4
  for (int i = 0; i < 1024; ++i) acc = fmaf(gs[i], Wd[(size_t)i*512 + j], acc);
  hfinal[b*512 + j] = h0[(size_t)(b*256 + 255)*512 + j] + acc;
}

// ---------------- MDN heads ----------------
__global__ void heads_musig(const float* __restrict__ last,
                            const float* __restrict__ W_mu, const float* __restrict__ b_mu,
                            const float* __restrict__ W_sig, const float* __restrict__ b_sig,
                            float* __restrict__ out)
{
  __shared__ float ls[512];
  int j = blockIdx.x*256 + threadIdx.x;
  int b = blockIdx.y, mat = blockIdx.z;
  for (int i = threadIdx.x; i < 512; i += 256) ls[i] = last[b*512 + i];
  __syncthreads();
  const float* W = mat ? W_sig : W_mu;
  const float* bb = mat ? b_sig : b_mu;
  float acc = bb[j];
  #pragma unroll 4
  for (int i = 0; i < 512; ++i) acc = fmaf(ls[i], W[(size_t)i*2048 + j], acc);
  float* dst = out + 128 + mat*8192 + b*2048 + j;
  *dst = mat ? softplus_f(acc) : acc;
}

__global__ void heads_pi(const float* __restrict__ last,
                         const float* __restrict__ W_pi, const float* __restrict__ b_pi,
                         float* __restrict__ out)
{
  __shared__ float ls[512];
  int b = blockIdx.x, o = threadIdx.x;
  for (int i = o; i < 512; i += 64) ls[i] = last[b*512 + i];
  __syncthreads();
  bool valid = o < 32;
  float acc = -3.4e38f;
  if (valid){
    acc = b_pi[o];
    for (int i = 0; i < 512; ++i) acc = fmaf(ls[i], W_pi[i*32 + o], acc);
  }
  float m = acc;
  #pragma unroll
  for (int o2 = 32; o2 > 0; o2 >>= 1) m = fmaxf(m, __shfl_xor(m, o2));
  float e = valid ? expf(acc - m) : 0.f;
  float ssum = e;
  #pragma unroll
  for (int o2 = 32; o2 > 0; o2 >>= 1) ssum += __shfl_xor(ssum, o2);
  if (valid) out[b*32 + o] = e / ssum;
}

// ---------------- launch ----------------
extern "C" void kernel_launch(void* const* d_in, const int* in_sizes, int n_in,
                              void* d_out, int out_size, void* d_ws, size_t ws_size,
                              hipStream_t stream)
{
  const float* x      = (const float*)d_in[0];
  const float* ln_s   = (const float*)d_in[1];
  const float* ln_b   = (const float*)d_in[2];
  const float* W_proj = (const float*)d_in[3];
  const float* Wq     = (const float*)d_in[4];
  const float* Wk     = (const float*)d_in[5];
  const float* Wv     = (const float*)d_in[6];
  const float* Wi     = (const float*)d_in[7];
  const float* bi     = (const float*)d_in[8];
  const float* Wf     = (const float*)d_in[9];
  const float* bf     = (const float*)d_in[10];
  const float* gn_s   = (const float*)d_in[11];
  const float* gn_b   = (const float*)d_in[12];
  const float* W_down = (const float*)d_in[13];
  const float* fln_s  = (const float*)d_in[14];
  const float* fln_b  = (const float*)d_in[15];
  const float* W_pi   = (const float*)d_in[16];
  const float* b_pi   = (const float*)d_in[17];
  const float* W_mu   = (const float*)d_in[18];
  const float* b_mu   = (const float*)d_in[19];
  const float* W_sig  = (const float*)d_in[20];
  const float* b_sig  = (const float*)d_in[21];
  float* out = (float*)d_out;

  float* ws = (float*)d_ws;
  float* xn     = ws;                    // 1024*512
  float* xp     = xn + 524288;           // 1024*2048
  float* qb     = xp + 2097152;          // 1024*1024
  float* kb     = qb + 1048576;          // 1024*1024
  float* vb     = kb + 1048576;          // 1024*1024
  float* ipfp   = vb + 1048576;          // 1024*16
  float* alpha  = ipfp + 16384;          // 32*256
  float* Mtb    = alpha + 8192;          // 32*256
  float* gated  = Mtb + 8192;            // 1024*1024
  float* h0     = gated + 1048576;       // 1024*512
  float* q1last = h0 + 524288;           // 4*1024
  float* gated1 = q1last + 4096;         // 4*1024
  float* hfinal = gated1 + 4096;         // 4*512
  float* lastb  = hfinal + 2048;         // 4*512

  const float INV_SQRT_DH = 0.08838834764831845f;  // 1/sqrt(128)
  dim3 blk256(256);

  // ---------- layer 0 ----------
  ln_rows<<<1024, blk256, 0, stream>>>(x, xn, ln_s, ln_b, 512);
  gemm_f32<<<dim3(32,16), blk256, 0, stream>>>(xn, 512, W_proj, xp, 2048, 1024, 512, 2048, 1.f, nullptr, 0);
  gemm_f32<<<dim3(16,16), blk256, 0, stream>>>(xp, 2048, Wq, qb, 1024, 1024, 1024, 1024, 1.f, nullptr, 0);
  gemm_f32<<<dim3(16,16), blk256, 0, stream>>>(xp, 2048, Wk, kb, 1024, 1024, 1024, 1024, INV_SQRT_DH, nullptr, 0);
  gemm_f32<<<dim3(16,16), blk256, 0, stream>>>(xp, 2048, Wv, vb, 1024, 1024, 1024, 1024, 1.f, nullptr, 0);
  ifgate<<<1024, blk256, 0, stream>>>(xp, Wi, bi, Wf, bf, ipfp);
  scan_gates<<<32, 64, 0, stream>>>(ipfp, alpha, Mtb);
  attn_l0<<<256, blk256, 0, stream>>>(qb, kb, vb, alpha, Mtb, xp, gn_s, gn_b, gated);
  gemm_f32<<<dim3(8,16), blk256, 0, stream>>>(gated, 1024, W_down, h0, 512, 1024, 1024, 512, 1.f, x, 512);

  // ---------- layer 1 ----------
  const float* ln_s1 = ln_s + 512;
  const float* ln_b1 = ln_b + 512;
  const float* Wp1   = W_proj + 512*2048;
  const float* Wq1   = Wq + 1024*1024;
  const float* Wk1   = Wk + 1024*1024;
  const float* Wv1   = Wv + 1024*1024;
  const float* Wi1   = Wi + 1024*8;
  const float* bi1   = bi + 8;
  const float* Wf1   = Wf + 1024*8;
  const float* bf1   = bf + 8;
  const float* gn_s1 = gn_s + 1024;
  const float* gn_b1 = gn_b + 1024;
  const float* Wd1   = W_down + 1024*512;

  ln_rows<<<1024, blk256, 0, stream>>>(h0, xn, ln_s1, ln_b1, 512);
  gemm_f32<<<dim3(32,16), blk256, 0, stream>>>(xn, 512, Wp1, xp, 2048, 1024, 512, 2048, 1.f, nullptr, 0);
  gemm_f32<<<dim3(16,16), blk256, 0, stream>>>(xp, 2048, Wk1, kb, 1024, 1024, 1024, 1024, INV_SQRT_DH, nullptr, 0);
  gemm_f32<<<dim3(16,16), blk256, 0, stream>>>(xp, 2048, Wv1, vb, 1024, 1024, 1024, 1024, 1.f, nullptr, 0);
  ifgate<<<1024, blk256, 0, stream>>>(xp, Wi1, bi1, Wf1, bf1, ipfp);
  scan_gates<<<32, 64, 0, stream>>>(ipfp, alpha, Mtb);
  qlast_kernel<<<dim3(4,4), blk256, 0, stream>>>(xp, Wq1, q1last);
  attn_l1<<<32, blk256, 0, stream>>>(q1last, kb, vb, alpha, Mtb, xp, gn_s1, gn_b1, gated1);
  downlast_kernel<<<dim3(2,4), blk256, 0, stream>>>(gated1, Wd1, h0, hfinal);

  // ---------- final head ----------
  ln_rows<<<4, blk256, 0, stream>>>(hfinal, lastb, fln_s, fln_b, 512);
  heads_musig<<<dim3(8,4,2), blk256, 0, stream>>>(lastb, W_mu, b_mu, W_sig, b_sig, out);
  heads_pi<<<4, 64, 0, stream>>>(lastb, W_pi, b_pi, out);
}

// Round 2
// 283.880 us; speedup vs baseline: 2.6300x; 2.6300x over previous
//
#include <hip/hip_runtime.h>
#include <hip/hip_bf16.h>
#include <math.h>

#define DEV __device__ __forceinline__

typedef __attribute__((ext_vector_type(8))) short bf16x8;
typedef __attribute__((ext_vector_type(4))) float f32x4;

static DEV float softplus_f(float x){ return fmaxf(x,0.f) + log1pf(expf(-fabsf(x))); }
static DEV float logsig_f(float x){ return fminf(x,0.f) - log1pf(expf(-fabsf(x))); }
static DEV float silu_f(float x){ return x / (1.f + expf(-x)); }
static DEV unsigned short f2bf(float f){
  union { float f; unsigned u; } v; v.f = f;
  unsigned r = (v.u + 0x7fffu + ((v.u >> 16) & 1u)) >> 16;
  return (unsigned short)r;
}

// ---------------- weight convert + transpose: W[K][M] fp32 -> Wt[M][K] bf16 ----------------
__global__ void wconv_all(const float* __restrict__ Wp, const float* __restrict__ Wq,
                          const float* __restrict__ Wk, const float* __restrict__ Wv,
                          const float* __restrict__ Wd,
                          unsigned short* projT0, unsigned short* projT1,
                          unsigned short* qT0, unsigned short* kT0, unsigned short* kT1,
                          unsigned short* vT0, unsigned short* vT1, unsigned short* dT0)
{
  int z = blockIdx.z;
  const float* W; unsigned short* Wt; int K, M; float scale = 1.f;
  const float INV = 0.08838834764831845f;  // 1/sqrt(128)
  switch (z){
    case 0: W = Wp;              Wt = projT0; K = 512;  M = 2048; break;
    case 1: W = Wp + 512*2048;   Wt = projT1; K = 512;  M = 2048; break;
    case 2: W = Wq;              Wt = qT0;    K = 1024; M = 1024; break;
    case 3: W = Wk;              Wt = kT0;    K = 1024; M = 1024; scale = INV; break;
    case 4: W = Wk + 1048576;    Wt = kT1;    K = 1024; M = 1024; scale = INV; break;
    case 5: W = Wv;              Wt = vT0;    K = 1024; M = 1024; break;
    case 6: W = Wv + 1048576;    Wt = vT1;    K = 1024; M = 1024; break;
    default: W = Wd;             Wt = dT0;    K = 1024; M = 512;  break;
  }
  int m0 = blockIdx.x * 32, k0 = blockIdx.y * 32;
  if (m0 >= M || k0 >= K) return;
  __shared__ float s[32][33];
  int tx = threadIdx.x & 31, ty = threadIdx.x >> 5;
  #pragma unroll
  for (int u = 0; u < 32; u += 8)
    s[ty+u][tx] = W[(size_t)(k0+ty+u)*M + m0 + tx];
  __syncthreads();
  #pragma unroll
  for (int u = 0; u < 32; u += 8)
    Wt[(size_t)(m0+ty+u)*K + k0 + tx] = f2bf(s[tx][ty+u] * scale);
}

// ---------------- LayerNorm over rows of width D; optional fp32 and bf16 outputs ----------------
__global__ void ln_rows(const float* __restrict__ in, float* __restrict__ outf,
                        unsigned short* __restrict__ outb,
                        const float* __restrict__ s, const float* __restrict__ b, int D)
{
  int r = blockIdx.x;
  const float* x = in + (size_t)r * D;
  float lsum = 0.f, lsq = 0.f;
  for (int i = threadIdx.x; i < D; i += blockDim.x){ float v = x[i]; lsum += v; lsq += v*v; }
  #pragma unroll
  for (int o = 32; o > 0; o >>= 1){ lsum += __shfl_down(lsum, o); lsq += __shfl_down(lsq, o); }
  __shared__ float s1[4], s2[4];
  int wid = threadIdx.x >> 6, lane = threadIdx.x & 63;
  if (lane == 0){ s1[wid] = lsum; s2[wid] = lsq; }
  __syncthreads();
  if (threadIdx.x == 0){ float a=0.f,c=0.f; for (int w=0; w<4; ++w){ a+=s1[w]; c+=s2[w]; } s1[0]=a; s2[0]=c; }
  __syncthreads();
  float mean = s1[0] / D, var = s2[0] / D - mean*mean;
  float rstd = rsqrtf(var + 1e-5f);
  for (int i = threadIdx.x; i < D; i += blockDim.x){
    float v = (x[i]-mean)*rstd*s[i] + b[i];
    if (outf) outf[(size_t)r*D + i] = v;
    if (outb) outb[(size_t)r*D + i] = f2bf(v);
  }
}

// ---------------- bf16 MFMA GEMM: C[N rows][M cols] = A[N][K]bf16 @ Bt[M][K]bf16^T ----------------
__global__ __launch_bounds__(256) void gemm_mfma(
    const unsigned short* __restrict__ A, int lda,
    const unsigned short* __restrict__ Bt, int ldb,
    float* __restrict__ C, int ldc,
    unsigned short* __restrict__ Cbf,                 // optional bf16 copy (same ldc)
    const float* __restrict__ skip, int ldskip,       // optional residual add
    int K)
{
  __shared__ __align__(16) unsigned short As[64][40];
  __shared__ __align__(16) unsigned short Bs[64][40];
  int row0 = blockIdx.y * 64, col0 = blockIdx.x * 64;
  int tid = threadIdx.x;
  int w = tid >> 6, l = tid & 63;
  int wr = (w >> 1) * 32, wc = (w & 1) * 32;
  int lr = l & 15, lk = l >> 4;
  int srow = tid >> 2, sk = (tid & 3) * 8;
  const unsigned short* aq = A  + (size_t)(row0 + srow) * lda + sk;
  const unsigned short* bq = Bt + (size_t)(col0 + srow) * ldb + sk;
  f32x4 acc00 = {0,0,0,0}, acc01 = {0,0,0,0}, acc10 = {0,0,0,0}, acc11 = {0,0,0,0};
  for (int k0 = 0; k0 < K; k0 += 32){
    *(bf16x8*)&As[srow][sk] = *(const bf16x8*)(aq + k0);
    *(bf16x8*)&Bs[srow][sk] = *(const bf16x8*)(bq + k0);
    __syncthreads();
    bf16x8 a0 = *(const bf16x8*)&As[wr + lr][lk*8];
    bf16x8 a1 = *(const bf16x8*)&As[wr + 16 + lr][lk*8];
    bf16x8 b0 = *(const bf16x8*)&Bs[wc + lr][lk*8];
    bf16x8 b1 = *(const bf16x8*)&Bs[wc + 16 + lr][lk*8];
    acc00 = __builtin_amdgcn_mfma_f32_16x16x32_bf16(a0, b0, acc00, 0, 0, 0);
    acc01 = __builtin_amdgcn_mfma_f32_16x16x32_bf16(a0, b1, acc01, 0, 0, 0);
    acc10 = __builtin_amdgcn_mfma_f32_16x16x32_bf16(a1, b0, acc10, 0, 0, 0);
    acc11 = __builtin_amdgcn_mfma_f32_16x16x32_bf16(a1, b1, acc11, 0, 0, 0);
    __syncthreads();
  }
  #pragma unroll
  for (int i = 0; i < 2; ++i){
    #pragma unroll
    for (int j = 0; j < 2; ++j){
      f32x4 a = (i == 0) ? ((j == 0) ? acc00 : acc01) : ((j == 0) ? acc10 : acc11);
      int col = col0 + wc + j*16 + lr;
      #pragma unroll
      for (int r = 0; r < 4; ++r){
        int row = row0 + wr + i*16 + lk*4 + r;
        float o = a[r];
        if (skip) o += skip[(size_t)row*ldskip + col];
        C[(size_t)row*ldc + col] = o;
        if (Cbf) Cbf[(size_t)row*ldc + col] = f2bf(o);
      }
    }
  }
}

// ---------------- input/forget gate preactivations: ipfp[r][0..7]=ip, [8..15]=fp ----------------
__global__ void ifgate(const float* __restrict__ xp,
                       const float* __restrict__ Wi, const float* __restrict__ bi,
                       const float* __restrict__ Wf, const float* __restrict__ bf,
                       float* __restrict__ ipfp)
{
  int r = blockIdx.x, tid = threadIdx.x;
  __shared__ float xs[1024];
  const float* xrow = xp + (size_t)r * 2048;   // xm = first 1024 cols
  for (int i = tid; i < 1024; i += 256) xs[i] = xrow[i];
  __syncthreads();
  int o = tid & 15, chunk = tid >> 4;
  const float* W = (o < 8) ? Wi : Wf;
  int oc = (o < 8) ? o : o - 8;
  float p = 0.f;
  #pragma unroll 8
  for (int u = 0; u < 64; ++u){ int kk = chunk*64 + u; p = fmaf(xs[kk], W[kk*8 + oc], p); }
  __shared__ float red[16][17];
  red[chunk][o] = p;
  __syncthreads();
  if (tid < 16){
    float sum = 0.f;
    for (int c2 = 0; c2 < 16; ++c2) sum += red[c2][tid];
    int oc2 = (tid < 8) ? tid : tid - 8;
    sum += (tid < 8) ? bi[oc2] : bf[oc2];
    ipfp[r*16 + tid] = sum;
  }
}

// ---------------- gate scan: alpha_s = ip_s - F_s, Mt_t = relu(running max alpha) ----------------
__global__ void scan_gates(const float* __restrict__ ipfp,
                           float* __restrict__ alpha, float* __restrict__ Mt)
{
  int bh = blockIdx.x; int b = bh >> 3, h = bh & 7;
  int lane = threadIdx.x;                 // 64 threads, 4 timesteps each
  float lf[4], ip[4];
  #pragma unroll
  for (int u = 0; u < 4; ++u){
    int t = lane*4 + u, r = b*256 + t;
    ip[u] = ipfp[r*16 + h];
    lf[u] = logsig_f(ipfp[r*16 + 8 + h]);
  }
  float c0 = lf[0], c1 = c0+lf[1], c2 = c1+lf[2], c3 = c2+lf[3];
  float tot = c3, pre = tot;
  #pragma unroll
  for (int o = 1; o < 64; o <<= 1){ float v = __shfl_up(pre, o); if (lane >= o) pre += v; }
  float excl = pre - tot;
  float F[4] = {excl+c0, excl+c1, excl+c2, excl+c3};
  float al[4];
  #pragma unroll
  for (int u = 0; u < 4; ++u) al[u] = ip[u] - F[u];
  float lm[4];
  lm[0] = al[0]; lm[1] = fmaxf(lm[0], al[1]); lm[2] = fmaxf(lm[1], al[2]); lm[3] = fmaxf(lm[2], al[3]);
  float pm = lm[3];
  #pragma unroll
  for (int o = 1; o < 64; o <<= 1){ float v = __shfl_up(pm, o); if (lane >= o) pm = fmaxf(pm, v); }
  float pmexcl = __shfl_up(pm, 1);
  if (lane == 0) pmexcl = -3.4e38f;
  int base = bh*256 + lane*4;
  #pragma unroll
  for (int u = 0; u < 4; ++u){
    alpha[base+u] = al[u];
    Mt[base+u] = fmaxf(0.f, fmaxf(pmexcl, lm[u]));
  }
}

// ---------------- fused causal weighted attention (layer 0, all t) + epilogue (bf16 out) ----------------
__global__ __launch_bounds__(256) void attn_l0(
    const float* __restrict__ q, const float* __restrict__ k, const float* __restrict__ v,
    const float* __restrict__ alpha, const float* __restrict__ Mt,
    const float* __restrict__ xp, const float* __restrict__ gn_s, const float* __restrict__ gn_b,
    unsigned short* __restrict__ gated)
{
  int blk = blockIdx.x;                    // ((b*8+h)*8 + tt)
  int tt = blk & 7, h = (blk >> 3) & 7, b = blk >> 6;
  int t0 = tt * 32;
  int tid = threadIdx.x;
  int bhT = ((b*8 + h) << 8);

  __shared__ float Qs[32][132];
  __shared__ float Ks[32][132];
  __shared__ float Vs[32][132];
  __shared__ float Ss[32][33];
  __shared__ float redS[8][32];
  __shared__ float redQ[8][32];

  { // load Q tile
    int rl = tid >> 3, c0 = (tid & 7) * 16;
    const float* qp = q + ((size_t)(b*256 + t0 + rl))*1024 + h*128 + c0;
    float4* dst = (float4*)&Qs[rl][c0];
    #pragma unroll
    for (int u = 0; u < 4; ++u) dst[u] = ((const float4*)qp)[u];
  }

  int tx = tid & 15, ty = tid >> 4;
  int tl = tid & 31, g = tid >> 5;
  float acc[16] = {};
  float den = 0.f;
  int ntile = tt + 1;

  for (int it = 0; it < ntile; ++it){
    int s0 = it * 32;
    { // load K,V tiles
      int rl = tid >> 3, c0 = (tid & 7) * 16;
      const float* kp = k + ((size_t)(b*256 + s0 + rl))*1024 + h*128 + c0;
      const float* vp = v + ((size_t)(b*256 + s0 + rl))*1024 + h*128 + c0;
      float4* kd = (float4*)&Ks[rl][c0];
      float4* vd = (float4*)&Vs[rl][c0];
      #pragma unroll
      for (int u = 0; u < 4; ++u){ kd[u] = ((const float4*)kp)[u]; vd[u] = ((const float4*)vp)[u]; }
    }
    __syncthreads();
    // phase A: 2t x 2s scores
    float s00=0.f, s01=0.f, s10=0.f, s11=0.f;
    #pragma unroll 8
    for (int d = 0; d < 128; d += 4){
      float4 qa0 = *(const float4*)&Qs[ty*2+0][d];
      float4 qa1 = *(const float4*)&Qs[ty*2+1][d];
      float4 kb0 = *(const float4*)&Ks[tx*2+0][d];
      float4 kb1 = *(const float4*)&Ks[tx*2+1][d];
      s00 += qa0.x*kb0.x + qa0.y*kb0.y + qa0.z*kb0.z + qa0.w*kb0.w;
      s01 += qa0.x*kb1.x + qa0.y*kb1.y + qa0.z*kb1.z + qa0.w*kb1.w;
      s10 += qa1.x*kb0.x + qa1.y*kb0.y + qa1.z*kb0.z + qa1.w*kb0.w;
      s11 += qa1.x*kb1.x + qa1.y*kb1.y + qa1.z*kb1.z + qa1.w*kb1.w;
    }
    #pragma unroll
    for (int i = 0; i < 2; ++i){
      int st = t0 + ty*2 + i;
      float mt = Mt[bhT + st];
      float sv[2] = { (i==0)? s00 : s10, (i==0)? s01 : s11 };
      #pragma unroll
      for (int j = 0; j < 2; ++j){
        int ss = s0 + tx*2 + j;
        float a = 0.f;
        if (ss <= st) a = expf(alpha[bhT + ss] - mt) * sv[j];
        Ss[ty*2+i][tx*2+j] = a;
      }
    }
    __syncthreads();
    // phase B: PV + row sum
    #pragma unroll 4
    for (int sl = 0; sl < 32; ++sl){
      float a = Ss[tl][sl];
      den += a;
      const float4* vr = (const float4*)&Vs[sl][g*16];
      float4 v0 = vr[0], v1 = vr[1], v2 = vr[2], v3 = vr[3];
      acc[0]  = fmaf(a, v0.x, acc[0]);  acc[1]  = fmaf(a, v0.y, acc[1]);
      acc[2]  = fmaf(a, v0.z, acc[2]);  acc[3]  = fmaf(a, v0.w, acc[3]);
      acc[4]  = fmaf(a, v1.x, acc[4]);  acc[5]  = fmaf(a, v1.y, acc[5]);
      acc[6]  = fmaf(a, v1.z, acc[6]);  acc[7]  = fmaf(a, v1.w, acc[7]);
      acc[8]  = fmaf(a, v2.x, acc[8]);  acc[9]  = fmaf(a, v2.y, acc[9]);
      acc[10] = fmaf(a, v2.z, acc[10]); acc[11] = fmaf(a, v2.w, acc[11]);
      acc[12] = fmaf(a, v3.x, acc[12]); acc[13] = fmaf(a, v3.y, acc[13]);
      acc[14] = fmaf(a, v3.z, acc[14]); acc[15] = fmaf(a, v3.w, acc[15]);
    }
    __syncthreads();
  }
  den = fmaxf(fabsf(den), 1.0f);
  float inv = 1.0f / den;
  float hh[16], ps = 0.f, pq = 0.f;
  #pragma unroll
  for (int j = 0; j < 16; ++j){ hh[j] = acc[j]*inv; ps += hh[j]; pq += hh[j]*hh[j]; }
  redS[g][tl] = ps; redQ[g][tl] = pq;
  __syncthreads();
  float sum = 0.f, sq = 0.f;
  #pragma unroll
  for (int g2 = 0; g2 < 8; ++g2){ sum += redS[g2][tl]; sq += redQ[g2][tl]; }
  float mean = sum * (1.f/128.f);
  float var  = sq  * (1.f/128.f) - mean*mean;
  float rstd = rsqrtf(var + 1e-5f);
  int r = b*256 + t0 + tl;
  const float* zrow = xp + (size_t)r*2048 + 1024 + h*128 + g*16;
  unsigned short* grow = gated + (size_t)r*1024 + h*128 + g*16;
  const float* gs = gn_s + h*128 + g*16;
  const float* gb = gn_b + h*128 + g*16;
  #pragma unroll
  for (int j = 0; j < 16; ++j){
    float valn = (hh[j]-mean)*rstd*gs[j] + gb[j];
    grow[j] = f2bf(valn * silu_f(zrow[j]));
  }
}

// ---------------- layer 1 q at last step: split-K GEMV ----------------
__global__ void qlast_split(const float* __restrict__ xp, const float* __restrict__ Wq1,
                            float* __restrict__ part)
{
  int jt = blockIdx.x, ks = blockIdx.y;      // (4, 32)
  int j = jt*256 + threadIdx.x;
  __shared__ float xs[4][32];
  int t = threadIdx.x;
  if (t < 128){ int b = t >> 5, kk = t & 31; xs[b][kk] = xp[(size_t)(b*256+255)*2048 + ks*32 + kk]; }
  __syncthreads();
  float a0=0.f,a1=0.f,a2=0.f,a3=0.f;
  #pragma unroll 8
  for (int kk = 0; kk < 32; ++kk){
    float wv = Wq1[(size_t)(ks*32+kk)*1024 + j];
    a0 = fmaf(xs[0][kk], wv, a0);
    a1 = fmaf(xs[1][kk], wv, a1);
    a2 = fmaf(xs[2][kk], wv, a2);
    a3 = fmaf(xs[3][kk], wv, a3);
  }
  part[((size_t)ks*4 + 0)*1024 + j] = a0;
  part[((size_t)ks*4 + 1)*1024 + j] = a1;
  part[((size_t)ks*4 + 2)*1024 + j] = a2;
  part[((size_t)ks*4 + 3)*1024 + j] = a3;
}

__global__ void qlast_reduce(const float* __restrict__ part, float* __restrict__ q1last)
{
  int j = blockIdx.x*256 + threadIdx.x;      // 4096 outputs
  float s = 0.f;
  for (int ks = 0; ks < 32; ++ks) s += part[(size_t)ks*4096 + j];
  q1last[j] = s;
}

// ---------------- layer 1: last-step attention + epilogue ----------------
__global__ __launch_bounds__(256) void attn_l1(
    const float* __restrict__ q1, const float* __restrict__ k1, const float* __restrict__ v1,
    const float* __restrict__ alpha, const float* __restrict__ Mt,
    const float* __restrict__ xp1, const float* __restrict__ gn_s, const float* __restrict__ gn_b,
    float* __restrict__ gated1)
{
  int bh = blockIdx.x; int b = bh >> 3, h = bh & 7;
  int tid = threadIdx.x;
  __shared__ float qsh[128];
  __shared__ float as[256];
  __shared__ float red2[2][128];
  __shared__ float hh_sh[128];
  __shared__ float wred[4];
  __shared__ float dsh, msh, rsh;
  if (tid < 128) qsh[tid] = q1[b*1024 + h*128 + tid];
  __syncthreads();
  float val;
  {
    int s = tid;
    const float* kp = k1 + ((size_t)(b*256 + s))*1024 + h*128;
    float sc = 0.f;
    #pragma unroll
    for (int d = 0; d < 128; d += 4){
      float4 kv = *(const float4*)(kp + d);
      sc += qsh[d]*kv.x + qsh[d+1]*kv.y + qsh[d+2]*kv.z + qsh[d+3]*kv.w;
    }
    float w = expf(alpha[bh*256 + s] - Mt[bh*256 + 255]);
    val = w * sc;
    as[s] = val;
  }
  float d = val;
  #pragma unroll
  for (int o = 32; o > 0; o >>= 1) d += __shfl_down(d, o);
  int wid = tid >> 6, lane = tid & 63;
  if (lane == 0) wred[wid] = d;
  __syncthreads();
  if (tid == 0){ float sum = wred[0]+wred[1]+wred[2]+wred[3]; dsh = fmaxf(fabsf(sum), 1.0f); }
  __syncthreads();
  int dh = tid & 127, half = tid >> 7;
  float np = 0.f;
  const float* vbase = v1 + ((size_t)(b*256))*1024 + h*128 + dh;
  for (int s2 = half*128; s2 < half*128 + 128; ++s2)
    np = fmaf(as[s2], vbase[(size_t)s2*1024], np);
  red2[half][dh] = np;
  __syncthreads();
  if (tid < 128) hh_sh[tid] = (red2[0][tid] + red2[1][tid]) / dsh;
  __syncthreads();
  if (tid < 64){
    float a = hh_sh[tid], c = hh_sh[tid+64];
    float s1 = a + c, s2v = a*a + c*c;
    #pragma unroll
    for (int o = 32; o > 0; o >>= 1){ s1 += __shfl_down(s1, o); s2v += __shfl_down(s2v, o); }
    if (tid == 0){
      float mean = s1*(1.f/128.f);
      float var = s2v*(1.f/128.f) - mean*mean;
      msh = mean; rsh = rsqrtf(var + 1e-5f);
    }
  }
  __syncthreads();
  if (tid < 128){
    int i = h*128 + tid;
    float valn = (hh_sh[tid]-msh)*rsh*gn_s[i] + gn_b[i];
    float z = xp1[(size_t)(b*256 + 255)*2048 + 1024 + i];
    gated1[b*1024 + i] = valn * silu_f(z);
  }
}

// ---------------- last-step down proj: split-K ----------------
__global__ void dl_split(const float* __restrict__ gated1, const float* __restrict__ Wd,
                         float* __restrict__ part)
{
  int jt = blockIdx.x, ks = blockIdx.y;      // (2, 32)
  int j = jt*256 + threadIdx.x;
  __shared__ float xs[4][32];
  int t = threadIdx.x;
  if (t < 128){ int b = t >> 5, kk = t & 31; xs[b][kk] = gated1[b*1024 + ks*32 + kk]; }
  __syncthreads();
  float a0=0.f,a1=0.f,a2=0.f,a3=0.f;
  #pragma unroll 8
  for (int kk = 0; kk < 32; ++kk){
    float wv = Wd[(size_t)(ks*32+kk)*512 + j];
    a0 = fmaf(xs[0][kk], wv, a0);
    a1 = fmaf(xs[1][kk], wv, a1);
    a2 = fmaf(xs[2][kk], wv, a2);
    a3 = fmaf(xs[3][kk], wv, a3);
  }
  part[((size_t)ks*4 + 0)*512 + j] = a0;
  part[((size_t)ks*4 + 1)*512 + j] = a1;
  part[((size_t)ks*4 + 2)*512 + j] = a2;
  part[((size_t)ks*4 + 3)*512 + j] = a3;
}

__global__ void dl_reduce(const float* __restrict__ part, const float* __restrict__ h0,
                          float* __restrict__ hfinal)
{
  int j2 = blockIdx.x*256 + threadIdx.x;     // 2048 outputs
  int b = j2 >> 9, jj = j2 & 511;
  float s = 0.f;
  for (int ks = 0; ks < 32; ++ks) s += part[((size_t)ks*4 + b)*512 + jj];
  hfinal[j2] = h0[(size_t)(b*256 + 255)*512 + jj] + s;
}

// ---------------- MDN mu/sigma heads: split-K ----------------
__global__ void ms_split(const float* __restrict__ last,
                         const float* __restrict__ W_mu, const float* __restrict__ W_sig,
                         float* __restrict__ part)
{
  int jt = blockIdx.x, ks = blockIdx.y, mat = blockIdx.z;  // (8, 8, 2)
  int j = jt*256 + threadIdx.x;
  const float* W = mat ? W_sig : W_mu;
  __shared__ float xs[4][64];
  int t = threadIdx.x;
  { int b = t >> 6, kk = t & 63; xs[b][kk] = last[b*512 + ks*64 + kk]; }
  __syncthreads();
  float a0=0.f,a1=0.f,a2=0.f,a3=0.f;
  #pragma unroll 8
  for (int kk = 0; kk < 64; ++kk){
    float wv = W[(size_t)(ks*64+kk)*2048 + j];
    a0 = fmaf(xs[0][kk], wv, a0);
    a1 = fmaf(xs[1][kk], wv, a1);
    a2 = fmaf(xs[2][kk], wv, a2);
    a3 = fmaf(xs[3][kk], wv, a3);
  }
  size_t base = ((size_t)(mat*8 + ks)*4);
  part[(base + 0)*2048 + j] = a0;
  part[(base + 1)*2048 + j] = a1;
  part[(base + 2)*2048 + j] = a2;
  part[(base + 3)*2048 + j] = a3;
}

__global__ void ms_reduce(const float* __restrict__ part,
                          const float* __restrict__ b_mu, const float* __restrict__ b_sig,
                          float* __restrict__ out)
{
  int j = blockIdx.x*256 + threadIdx.x;      // 2048
  int b = blockIdx.y, mat = blockIdx.z;
  float s = mat ? b_sig[j] : b_mu[j];
  for (int ks = 0; ks < 8; ++ks) s += part[((size_t)(mat*8 + ks)*4 + b)*2048 + j];
  out[128 + mat*8192 + b*2048 + j] = mat ? softplus_f(s) : s;
}

// ---------------- pi head ----------------
__global__ void heads_pi(const float* __restrict__ last,
                         const float* __restrict__ W_pi, const float* __restrict__ b_pi,
                         float* __restrict__ out)
{
  __shared__ float ls[512];
  int b = blockIdx.x, o = threadIdx.x;
  for (int i = o; i < 512; i += 64) ls[i] = last[b*512 + i];
  __syncthreads();
  bool valid = o < 32;
  float acc = -3.4e38f;
  if (valid){
    acc = b_pi[o];
    for (int i = 0; i < 512; ++i) acc = fmaf(ls[i], W_pi[i*32 + o], acc);
  }
  float m = acc;
  #pragma unroll
  for (int o2 = 32; o2 > 0; o2 >>= 1) m = fmaxf(m, __shfl_xor(m, o2));
  float e = valid ? expf(acc - m) : 0.f;
  float ssum = e;
  #pragma unroll
  for (int o2 = 32; o2 > 0; o2 >>= 1) ssum += __shfl_xor(ssum, o2);
  if (valid) out[b*32 + o] = e / ssum;
}

// ---------------- launch ----------------
extern "C" void kernel_launch(void* const* d_in, const int* in_sizes, int n_in,
                              void* d_out, int out_size, void* d_ws, size_t ws_size,
                              hipStream_t stream)
{
  const float* x      = (const float*)d_in[0];
  const float* ln_s   = (const float*)d_in[1];
  const float* ln_b   = (const float*)d_in[2];
  const float* W_proj = (const float*)d_in[3];
  const float* Wq     = (const float*)d_in[4];
  const float* Wk     = (const float*)d_in[5];
  const float* Wv     = (const float*)d_in[6];
  const float* Wi     = (const float*)d_in[7];
  const float* bi     = (const float*)d_in[8];
  const float* Wf     = (const float*)d_in[9];
  const float* bf     = (const float*)d_in[10];
  const float* gn_s   = (const float*)d_in[11];
  const float* gn_b   = (const float*)d_in[12];
  const float* W_down = (const float*)d_in[13];
  const float* fln_s  = (const float*)d_in[14];
  const float* fln_b  = (const float*)d_in[15];
  const float* W_pi   = (const float*)d_in[16];
  const float* b_pi   = (const float*)d_in[17];
  const float* W_mu   = (const float*)d_in[18];
  const float* b_mu   = (const float*)d_in[19];
  const float* W_sig  = (const float*)d_in[20];
  const float* b_sig  = (const float*)d_in[21];
  float* out = (float*)d_out;

  char* p = (char*)d_ws;
  unsigned short* projT0 = (unsigned short*)p; p += (size_t)2048*512*2;
  unsigned short* projT1 = (unsigned short*)p; p += (size_t)2048*512*2;
  unsigned short* qT0    = (unsigned short*)p; p += (size_t)1024*1024*2;
  unsigned short* kT0    = (unsigned short*)p; p += (size_t)1024*1024*2;
  unsigned short* kT1    = (unsigned short*)p; p += (size_t)1024*1024*2;
  unsigned short* vT0    = (unsigned short*)p; p += (size_t)1024*1024*2;
  unsigned short* vT1    = (unsigned short*)p; p += (size_t)1024*1024*2;
  unsigned short* dT0    = (unsigned short*)p; p += (size_t)512*1024*2;
  unsigned short* xnb    = (unsigned short*)p; p += (size_t)1024*512*2;
  float* xp     = (float*)p; p += (size_t)1024*2048*4;
  unsigned short* xpb = (unsigned short*)p; p += (size_t)1024*2048*2;
  float* qb     = (float*)p; p += (size_t)1024*1024*4;
  float* kb     = (float*)p; p += (size_t)1024*1024*4;
  float* vb     = (float*)p; p += (size_t)1024*1024*4;
  unsigned short* gatedb = (unsigned short*)p; p += (size_t)1024*1024*2;
  float* h0     = (float*)p; p += (size_t)1024*512*4;
  float* ipfp   = (float*)p; p += (size_t)16384*4;
  float* alpha  = (float*)p; p += (size_t)8192*4;
  float* Mtb    = (float*)p; p += (size_t)8192*4;
  float* q1last = (float*)p; p += (size_t)4096*4;
  float* gated1 = (float*)p; p += (size_t)4096*4;
  float* hfinal = (float*)p; p += (size_t)2048*4;
  float* lastb  = (float*)p; p += (size_t)2048*4;
  float* qpart  = (float*)p; p += (size_t)32*4096*4;
  float* dpart  = (float*)p; p += (size_t)32*4*512*4;
  float* mspart = (float*)p; p += (size_t)16*4*2048*4;

  const float* ln_s1 = ln_s + 512;
  const float* ln_b1 = ln_b + 512;
  const float* Wi1   = Wi + 1024*8;
  const float* bi1   = bi + 8;
  const float* Wf1   = Wf + 1024*8;
  const float* bf1   = bf + 8;
  const float* gn_s1 = gn_s + 1024;
  const float* gn_b1 = gn_b + 1024;
  const float* Wq1   = Wq + 1024*1024;
  const float* Wd1   = W_down + 1024*512;

  dim3 blk256(256);

  // weight convert + transpose (bf16)
  wconv_all<<<dim3(64,32,8), blk256, 0, stream>>>(W_proj, Wq, Wk, Wv, W_down,
      projT0, projT1, qT0, kT0, kT1, vT0, vT1, dT0);

  // ---------- layer 0 ----------
  ln_rows<<<1024, blk256, 0, stream>>>(x, nullptr, xnb, ln_s, ln_b, 512);
  gemm_mfma<<<dim3(32,16), blk256, 0, stream>>>(xnb, 512, projT0, 512, xp, 2048, xpb, nullptr, 0, 512);
  gemm_mfma<<<dim3(16,16), blk256, 0, stream>>>(xpb, 2048, qT0, 1024, qb, 1024, nullptr, nullptr, 0, 1024);
  gemm_mfma<<<dim3(16,16), blk256, 0, stream>>>(xpb, 2048, kT0, 1024, kb, 1024, nullptr, nullptr, 0, 1024);
  gemm_mfma<<<dim3(16,16), blk256, 0, stream>>>(xpb, 2048, vT0, 1024, vb, 1024, nullptr, nullptr, 0, 1024);
  ifgate<<<1024, blk256, 0, stream>>>(xp, Wi, bi, Wf, bf, ipfp);
  scan_gates<<<32, 64, 0, stream>>>(ipfp, alpha, Mtb);
  attn_l0<<<256, blk256, 0, stream>>>(qb, kb, vb, alpha, Mtb, xp, gn_s, gn_b, gatedb);
  gemm_mfma<<<dim3(8,16), blk256, 0, stream>>>(gatedb, 1024, dT0, 1024, h0, 512, nullptr, x, 512, 1024);

  // ---------- layer 1 ----------
  ln_rows<<<1024, blk256, 0, stream>>>(h0, nullptr, xnb, ln_s1, ln_b1, 512);
  gemm_mfma<<<dim3(32,16), blk256, 0, stream>>>(xnb, 512, projT1, 512, xp, 2048, xpb, nullptr, 0, 512);
  gemm_mfma<<<dim3(16,16), blk256, 0, stream>>>(xpb, 2048, kT1, 1024, kb, 1024, nullptr, nullptr, 0, 1024);
  gemm_mfma<<<dim3(16,16), blk256, 0, stream>>>(xpb, 2048, vT1, 1024, vb, 1024, nullptr, nullptr, 0, 1024);
  ifgate<<<1024, blk256, 0, stream>>>(xp, Wi1, bi1, Wf1, bf1, ipfp);
  scan_gates<<<32, 64, 0, stream>>>(ipfp, alpha, Mtb);
  qlast_split<<<dim3(4,32), blk256, 0, stream>>>(xp, Wq1, qpart);
  qlast_reduce<<<16, blk256, 0, stream>>>(qpart, q1last);
  attn_l1<<<32, blk256, 0, stream>>>(q1last, kb, vb, alpha, Mtb, xp, gn_s1, gn_b1, gated1);
  dl_split<<<dim3(2,32), blk256, 0, stream>>>(gated1, Wd1, dpart);
  dl_reduce<<<8, blk256, 0, stream>>>(dpart, h0, hfinal);

  // ---------- final head ----------
  ln_rows<<<4, blk256, 0, stream>>>(hfinal, lastb, nullptr, fln_s, fln_b, 512);
  ms_split<<<dim3(8,8,2), blk256, 0, stream>>>(lastb, W_mu, W_sig, mspart);
  ms_reduce<<<dim3(8,4,2), blk256, 0, stream>>>(mspart, b_mu, b_sig, out);
  heads_pi<<<4, 64, 0, stream>>>(lastb, W_pi, b_pi, out);
}